// Round 12
// baseline (273.893 us; speedup 1.0000x reference)
//
#include <hip/hip_runtime.h>
#include <math.h>

// Problem constants
#define B_ 4
#define HH 64
#define WW 64
#define LL 4096          // H*W
#define DM 96            // d_model
#define DI 192           // d_inner
#define NS 16            // n_state
#define RR 6             // r_rank
#define KK 4             // directions
#define NROW (B_ * KK * DI)   // 3072 scan rows
#define XPS 160          // xdblP row stride per pixel (4 dirs x 40)
#define KOFF 40          // per-direction block within a row (38 real + 2 pad)

__device__ __forceinline__ int pix_of(int k, int l) {
    switch (k) {
        case 0: return l;
        case 1: { int w = l >> 6, h = l & 63; return (h << 6) + w; }
        case 2: return (LL - 1) - l;
        default: { int ll = (LL - 1) - l; int w = ll >> 6, h = ll & 63; return (h << 6) + w; }
    }
}

// Fast math (native v_exp_f32 / v_log_f32 / v_rcp_f32)
__device__ __forceinline__ float silu_f(float v) {
    return v * __fdividef(1.f, 1.f + __expf(-v));
}
__device__ __forceinline__ float softplus_f(float x) {
    return (x > 20.f) ? x : __logf(1.f + __expf(x));
}

// ---------------- GEMM: C[M,N] = A[M,K] * Bw[N,K]^T ----------------
// Transposed LDS tiles (k-major): inner loop = 2x ds_read_b128 + 16 FMA.
// MODE 0: in_proj epilogue (n<192 -> C0 raw; else silu -> C1)
// MODE 1: plain store C0[M,N]
// MODE 2: xdbl epilogue: n<152 -> C0[m*160 + (n/38)*40 + n%38]
template<int MODE>
__global__ __launch_bounds__(256)
void gemm_kernel(const float* __restrict__ A, const float* __restrict__ Bw,
                 float* __restrict__ C0, float* __restrict__ C1,
                 int M, int N, int Kd) {
    __shared__ float As[32][68];   // [k][m] ; 68*4B = 17*16B -> b128-aligned rows
    __shared__ float Bs[32][68];   // [k][n]
    int tid = threadIdx.x;
    int tx = tid & 15, ty = tid >> 4;
    int m0 = blockIdx.y * 64, n0 = blockIdx.x * 64;
    float acc[4][4] = {};
    for (int k0 = 0; k0 < Kd; k0 += 32) {
        #pragma unroll
        for (int i = 0; i < 8; ++i) {
            int idx = tid + i * 256;
            int r = idx >> 5, c = idx & 31;
            As[c][r] = A[(size_t)(m0 + r) * Kd + k0 + c];
            int rn = n0 + r;
            Bs[c][r] = (rn < N) ? Bw[(size_t)rn * Kd + k0 + c] : 0.f;
        }
        __syncthreads();
        #pragma unroll
        for (int kk = 0; kk < 32; ++kk) {
            float4 av = *(const float4*)&As[kk][ty * 4];
            float4 bv = *(const float4*)&Bs[kk][tx * 4];
            const float* avp = (const float*)&av;
            const float* bvp = (const float*)&bv;
            #pragma unroll
            for (int i = 0; i < 4; ++i)
                #pragma unroll
                for (int j = 0; j < 4; ++j)
                    acc[i][j] += avp[i] * bvp[j];
        }
        __syncthreads();
    }
    #pragma unroll
    for (int i = 0; i < 4; ++i) {
        int m = m0 + ty * 4 + i;
        #pragma unroll
        for (int j = 0; j < 4; ++j) {
            int n = n0 + tx * 4 + j;
            if (n >= N) continue;
            float v = acc[i][j];
            if (MODE == 0) {
                if (n < DI) C0[(size_t)m * DI + n] = v;
                else        C1[(size_t)m * DI + (n - DI)] = silu_f(v);
            } else if (MODE == 1) {
                C0[(size_t)m * N + n] = v;
            } else {
                if (n < 152) {
                    int kd = n / 38, c = n - kd * 38;
                    C0[(size_t)m * XPS + kd * KOFF + c] = v;
                }
            }
        }
    }
}

// ---------------- Depthwise 3x3 conv + bias + SiLU, 8-pixel row tile ----------------
__global__ __launch_bounds__(192)
void conv_kernel(const float* __restrict__ xc, const float* __restrict__ cw,
                 const float* __restrict__ cb, float* __restrict__ out) {
    int p0 = blockIdx.x * 8;     // 8 pixels, same row (8 | 64)
    int b = blockIdx.y;
    int c = threadIdx.x;
    int h = p0 >> 6, w0 = p0 & 63;
    float kw[9];
    #pragma unroll
    for (int j = 0; j < 9; ++j) kw[j] = cw[c * 9 + j];
    float xv[3][10];
    #pragma unroll
    for (int dh = 0; dh < 3; ++dh) {
        int hh = h + dh - 1;
        bool hv = (hh >= 0 && hh < HH);
        #pragma unroll
        for (int j = 0; j < 10; ++j) {
            int ww = w0 + j - 1;
            bool v = hv && (ww >= 0 && ww < WW);
            xv[dh][j] = v ? xc[((size_t)(b << 12) + (hh << 6) + ww) * DI + c] : 0.f;
        }
    }
    float bias = cb[c];
    #pragma unroll
    for (int w = 0; w < 8; ++w) {
        float acc = bias;
        #pragma unroll
        for (int dh = 0; dh < 3; ++dh)
            #pragma unroll
            for (int dc = 0; dc < 3; ++dc)
                acc += xv[dh][w + dc] * kw[dh * 3 + dc];
        out[((size_t)(b << 12) + p0 + w) * DI + c] = silu_f(acc);
    }
}

// ---------------- prep: fastA flag (flag=0 -> A[n] == -(n+1) everywhere) ----------------
__global__ __launch_bounds__(256)
void prep_kernel(const float* __restrict__ A_logs, int* __restrict__ flag) {
    int t = blockIdx.x * 256 + threadIdx.x;
    if (t >= KK * DI * NS) return;
    int n = t & 15;
    float an = -__expf(A_logs[t]);
    if (!(fabsf(an + (float)(n + 1)) < 1e-4f * (float)(n + 1))) atomicOr(flag, 1);
}

// ---------------- Paired scan phases ----------------
// Block = 192 threads (one d each). pair = blockIdx.y: (k0,k1) = (pair, pair+2).
// Block owns k0's chunk c walked FORWARD and k1's chunk NCHT-1-c walked BACKWARD
// over the SAME pixel window [p0 + r*s], r=0..CHL-1 (s = 1 or 64).
// xdbl rows are wave-uniform -> direct global reads; loop fully unrolled so the
// compiler pipelines the row loads across steps. Phase 3 accumulates y in
// REGISTERS (static indices) and does CHL coalesced stores (no LDS, no atomics).
// pair0 writes yA, pair1 writes yB; LN sums them.
// carryB layout: [chunk][row][n]; sumD: [chunk][row]; row = (b*K+k)*DI+d.
template<int PHASE, int NCHT>
__global__ __launch_bounds__(192)
void scan_paired(const float* __restrict__ xconv, const float* __restrict__ xdblP,
                 const float* __restrict__ dtw, const float* __restrict__ dtb,
                 const float* __restrict__ A_logs, const float* __restrict__ Ds,
                 float* __restrict__ sumD, float* __restrict__ carryB,
                 float* __restrict__ yA, float* __restrict__ yB,
                 const int* __restrict__ flag) {
    constexpr int CHL = LL / NCHT;
    constexpr int NV4 = (PHASE == 3) ? (KOFF / 4) : 6;
    int c = blockIdx.x;
    int pair = blockIdx.y;
    int b = blockIdx.z;
    int d = threadIdx.x;
    int k0 = pair, k1 = pair + 2;
    int c2 = NCHT - 1 - c;
    int s = (pair == 0) ? 1 : 64;
    int p0 = pix_of(k0, c * CHL);

    float wr0[RR], wr1[RR];
    #pragma unroll
    for (int r = 0; r < RR; ++r) {
        wr0[r] = dtw[(k0 * DI + d) * RR + r];
        wr1[r] = dtw[(k1 * DI + d) * RR + r];
    }
    float bias0 = dtb[k0 * DI + d], bias1 = dtb[k1 * DI + d];
    const float* alog0 = A_logs + (size_t)(k0 * DI + d) * NS;
    const float* alog1 = A_logs + (size_t)(k1 * DI + d) * NS;
    bool fastA = (*flag == 0);
    int row0 = (b * KK + k0) * DI + d;
    int row1 = (b * KK + k1) * DI + d;
    float h0[NS], h1[NS];
    if (PHASE == 1) {
        #pragma unroll
        for (int n = 0; n < NS; ++n) { h0[n] = 0.f; h1[n] = 0.f; }
    } else {
        const float4* ca = (const float4*)(carryB + ((size_t)c * NROW + row0) * NS);
        const float4* cb = (const float4*)(carryB + ((size_t)c2 * NROW + row1) * NS);
        #pragma unroll
        for (int q = 0; q < NS / 4; ++q) {
            float4 va = ca[q], vb = cb[q];
            h0[q * 4 + 0] = va.x; h0[q * 4 + 1] = va.y; h0[q * 4 + 2] = va.z; h0[q * 4 + 3] = va.w;
            h1[q * 4 + 0] = vb.x; h1[q * 4 + 1] = vb.y; h1[q * 4 + 2] = vb.z; h1[q * 4 + 3] = vb.w;
        }
    }
    float Dk0 = (PHASE == 3) ? Ds[k0 * DI + d] : 0.f;
    float Dk1 = (PHASE == 3) ? Ds[k1 * DI + d] : 0.f;
    float sum0 = 0.f, sum1 = 0.f;
    const float* ub = xconv + ((size_t)(b << 12) + p0) * DI + d;
    const float* xrow = xdblP + ((size_t)(b << 12) + p0) * XPS;
    intptr_t xstp = (intptr_t)s * XPS;
    intptr_t ustp = (intptr_t)s * DI;

    float yreg[(PHASE == 3) ? CHL : 1];
    if (PHASE == 3) {
        #pragma unroll
        for (int r = 0; r < CHL; ++r) yreg[r] = 0.f;
    }

    auto dstep = [&](const float* __restrict__ xr, float u, const float* wr, float biasv,
                     const float* alog, float Dkv, float* h, float& sd) -> float {
        float xrv[NV4 * 4];
        #pragma unroll
        for (int j = 0; j < NV4; ++j) ((float4*)xrv)[j] = ((const float4*)xr)[j];
        float dtraw = biasv;
        #pragma unroll
        for (int r = 0; r < RR; ++r) dtraw += xrv[r] * wr[r];
        float delta = softplus_f(dtraw);
        if (PHASE == 1) sd += delta;
        float du = delta * u;
        float y = 0.f;
        if (fastA) {
            float g = __expf(-delta);
            float a = 1.f;
            #pragma unroll
            for (int n = 0; n < NS; ++n) {
                a *= g;                       // a = g^(n+1) = exp(-(n+1)*delta)
                h[n] = a * h[n] + du * xrv[6 + n];
                if (PHASE == 3) y += h[n] * xrv[22 + n];
            }
        } else {
            #pragma unroll
            for (int n = 0; n < NS; ++n) {
                float a = __expf(delta * (-__expf(alog[n])));
                h[n] = a * h[n] + du * xrv[6 + n];
                if (PHASE == 3) y += h[n] * xrv[22 + n];
            }
        }
        if (PHASE == 3) y += u * Dkv;
        return y;
    };

    #pragma unroll
    for (int i = 0; i < CHL; ++i) {
        int ri = CHL - 1 - i;
        float u0 = ub[(intptr_t)i * ustp];
        float u1 = ub[(intptr_t)ri * ustp];
        float y0 = dstep(xrow + (intptr_t)i * xstp + k0 * KOFF, u0, wr0, bias0, alog0, Dk0, h0, sum0);
        float y1 = dstep(xrow + (intptr_t)ri * xstp + k1 * KOFF, u1, wr1, bias1, alog1, Dk1, h1, sum1);
        if (PHASE == 3) {
            yreg[i] += y0;               // static indices (full unroll): stays in VGPRs
            yreg[ri] += y1;
        }
    }

    if (PHASE == 3) {
        float* yo = ((pair == 0) ? yA : yB) + ((size_t)(b << 12) + p0) * DI + d;
        #pragma unroll
        for (int r = 0; r < CHL; ++r) yo[(intptr_t)r * ustp] = yreg[r];
    } else {
        float4* ca = (float4*)(carryB + ((size_t)c * NROW + row0) * NS);
        float4* cb = (float4*)(carryB + ((size_t)c2 * NROW + row1) * NS);
        #pragma unroll
        for (int q = 0; q < NS / 4; ++q) {
            float4 va, vb;
            va.x = h0[q * 4 + 0]; va.y = h0[q * 4 + 1]; va.z = h0[q * 4 + 2]; va.w = h0[q * 4 + 3];
            vb.x = h1[q * 4 + 0]; vb.y = h1[q * 4 + 1]; vb.z = h1[q * 4 + 2]; vb.w = h1[q * 4 + 3];
            ca[q] = va; cb[q] = vb;
        }
        sumD[(size_t)c * NROW + row0] = sum0;
        sumD[(size_t)c2 * NROW + row1] = sum1;
    }
}

// ---------------- Phase 2: sequential scan over chunk carries ----------------
// a(chunk) reconstructed exactly: prod_i exp(An*d_i) == exp(An * sum d_i)
template<int NCHT>
__global__ __launch_bounds__(256)
void scan_chunks(const float* __restrict__ sumD, const float* __restrict__ A_logs,
                 float* __restrict__ carryB) {
    int t = blockIdx.x * 256 + threadIdx.x;
    if (t >= NROW * NS) return;
    int row = t >> 4, n = t & 15;
    int kd = row % (KK * DI);
    float An = -__expf(A_logs[(size_t)kd * NS + n]);
    float h = 0.f;
    #pragma unroll 4
    for (int c = 0; c < NCHT; ++c) {
        size_t idx = (size_t)c * (NROW * NS) + t;
        float bb = carryB[idx];
        carryB[idx] = h;       // exclusive prefix = h_in for chunk c
        float a = __expf(An * sumD[(size_t)c * NROW + row]);
        h = a * h + bb;
    }
}

// ---------------- LayerNorm * z  (y = yA + yB) ----------------
__global__ __launch_bounds__(256)
void ln_kernel(const float* __restrict__ yA, const float* __restrict__ yB,
               const float* __restrict__ z_silu,
               const float* __restrict__ nw, const float* __restrict__ nb,
               float* __restrict__ out) {
    int pg = blockIdx.x * 4 + (threadIdx.x >> 6);
    int lane = threadIdx.x & 63;
    const float* ya = yA + (size_t)pg * DI;
    const float* yb = yB + (size_t)pg * DI;
    float v0 = ya[lane] + yb[lane];
    float v1 = ya[lane + 64] + yb[lane + 64];
    float v2 = ya[lane + 128] + yb[lane + 128];
    float s = v0 + v1 + v2;
    float sq = v0 * v0 + v1 * v1 + v2 * v2;
    #pragma unroll
    for (int m = 32; m >= 1; m >>= 1) {
        s  += __shfl_xor(s, m, 64);
        sq += __shfl_xor(sq, m, 64);
    }
    float mu = s * (1.f / 192.f);
    float var = sq * (1.f / 192.f) - mu * mu;
    float rs = rsqrtf(var + 1e-5f);
    const float* zr = z_silu + (size_t)pg * DI;
    float* o = out + (size_t)pg * DI;
    float vv[3] = {v0, v1, v2};
    #pragma unroll
    for (int j = 0; j < 3; ++j) {
        int c = lane + j * 64;
        o[c] = (nw[c] * (vv[j] - mu) * rs + nb[c]) * zr[c];
    }
}

extern "C" void kernel_launch(void* const* d_in, const int* in_sizes, int n_in,
                              void* d_out, int out_size, void* d_ws, size_t ws_size,
                              hipStream_t stream) {
    const float* x        = (const float*)d_in[0];
    const float* in_projw = (const float*)d_in[1];
    const float* conv_w   = (const float*)d_in[2];
    const float* conv_b   = (const float*)d_in[3];
    const float* x_projw  = (const float*)d_in[4];
    const float* dt_w     = (const float*)d_in[5];
    const float* dt_b     = (const float*)d_in[6];
    const float* A_logs   = (const float*)d_in[7];
    const float* Ds       = (const float*)d_in[8];
    const float* nw       = (const float*)d_in[9];
    const float* nb       = (const float*)d_in[10];
    const float* opw      = (const float*)d_in[11];
    float* out = (float*)d_out;
    float* ws = (float*)d_ws;

    const size_t SZ = (size_t)B_ * LL * DI;          // 3,145,728
    const size_t XD = (size_t)B_ * LL * XPS;         // 2,621,440
    const size_t CAR256 = (size_t)NROW * 256 * NS;   // 12,582,912
    const size_t CAR128 = (size_t)NROW * 128 * NS;   //  6,291,456
    const size_t need256 = (4 * SZ + XD + CAR256 + (size_t)NROW * 256 + 16) * sizeof(float);
    bool big = (ws_size >= need256);
    const size_t CAR = big ? CAR256 : CAR128;
    const int NCH = big ? 256 : 128;

    float* z_silu = ws;
    float* yA     = ws + SZ;            // in_proj staging (xc_raw), reused as yA
    float* xconv  = ws + 2 * SZ;        // reused as yln after phase 3
    float* yB     = ws + 3 * SZ;
    float* xdblP  = ws + 4 * SZ;
    float* carryB = ws + 4 * SZ + XD;
    float* sumD   = carryB + CAR;
    int*   flag   = (int*)(sumD + (size_t)NROW * NCH);
    float* xc_raw = yA;
    float* yln    = xconv;

    gemm_kernel<0><<<dim3(6, 256), 256, 0, stream>>>(x, in_projw, xc_raw, z_silu,
                                                     B_ * LL, 2 * DI, DM);
    hipMemsetAsync(flag, 0, sizeof(int), stream);
    prep_kernel<<<(KK * DI * NS + 255) / 256, 256, 0, stream>>>(A_logs, flag);
    conv_kernel<<<dim3(LL / 8, B_), DI, 0, stream>>>(xc_raw, conv_w, conv_b, xconv);
    // x_dbl for all 4 directions in one pixel-order GEMM (152 = 4*38 outputs)
    gemm_kernel<2><<<dim3(3, 256), 256, 0, stream>>>(xconv, x_projw, xdblP, nullptr,
                                                     B_ * LL, 152, DI);

    if (big) {
        scan_paired<1, 256><<<dim3(256, 2, B_), 192, 0, stream>>>(xconv, xdblP, dt_w, dt_b,
                                                                  A_logs, Ds, sumD, carryB, nullptr, nullptr, flag);
        scan_chunks<256><<<(NROW * NS + 255) / 256, 256, 0, stream>>>(sumD, A_logs, carryB);
        scan_paired<3, 256><<<dim3(256, 2, B_), 192, 0, stream>>>(xconv, xdblP, dt_w, dt_b,
                                                                  A_logs, Ds, sumD, carryB, yA, yB, flag);
    } else {
        scan_paired<1, 128><<<dim3(128, 2, B_), 192, 0, stream>>>(xconv, xdblP, dt_w, dt_b,
                                                                  A_logs, Ds, sumD, carryB, nullptr, nullptr, flag);
        scan_chunks<128><<<(NROW * NS + 255) / 256, 256, 0, stream>>>(sumD, A_logs, carryB);
        scan_paired<3, 128><<<dim3(128, 2, B_), 192, 0, stream>>>(xconv, xdblP, dt_w, dt_b,
                                                                  A_logs, Ds, sumD, carryB, yA, yB, flag);
    }
    ln_kernel<<<(B_ * LL) / 4, 256, 0, stream>>>(yA, yB, z_silu, nw, nb, yln);
    gemm_kernel<1><<<dim3(2, 256), 256, 0, stream>>>(yln, opw, out, nullptr,
                                                     B_ * LL, DM, DI);
}

// Round 13
// 249.316 us; speedup vs baseline: 1.0986x; 1.0986x over previous
//
#include <hip/hip_runtime.h>
#include <math.h>

// Problem constants
#define B_ 4
#define HH 64
#define WW 64
#define LL 4096          // H*W
#define DM 96            // d_model
#define DI 192           // d_inner
#define NS 16            // n_state
#define RR 6             // r_rank
#define KK 4             // directions
#define NROW (B_ * KK * DI)   // 3072 scan rows
#define XPS 160          // xdblP row stride per pixel (4 dirs x 40)
#define KOFF 40          // per-direction block within a row (38 real + 2 pad)

__device__ __forceinline__ int pix_of(int k, int l) {
    switch (k) {
        case 0: return l;
        case 1: { int w = l >> 6, h = l & 63; return (h << 6) + w; }
        case 2: return (LL - 1) - l;
        default: { int ll = (LL - 1) - l; int w = ll >> 6, h = ll & 63; return (h << 6) + w; }
    }
}

// Fast math (native v_exp_f32 / v_log_f32 / v_rcp_f32)
__device__ __forceinline__ float silu_f(float v) {
    return v * __fdividef(1.f, 1.f + __expf(-v));
}
__device__ __forceinline__ float softplus_f(float x) {
    return (x > 20.f) ? x : __logf(1.f + __expf(x));
}

// ---------------- GEMM: C[M,N] = A[M,K] * Bw[N,K]^T ----------------
// Transposed LDS tiles (k-major): inner loop = 2x ds_read_b128 + 16 FMA.
// MODE 0: in_proj epilogue (n<192 -> C0 raw; else silu -> C1)
// MODE 1: plain store C0[M,N]
// MODE 2: xdbl epilogue: n<152 -> C0[m*160 + (n/38)*40 + n%38]
template<int MODE>
__global__ __launch_bounds__(256)
void gemm_kernel(const float* __restrict__ A, const float* __restrict__ Bw,
                 float* __restrict__ C0, float* __restrict__ C1,
                 int M, int N, int Kd) {
    __shared__ float As[32][68];   // [k][m] ; 68*4B = 17*16B -> b128-aligned rows
    __shared__ float Bs[32][68];   // [k][n]
    int tid = threadIdx.x;
    int tx = tid & 15, ty = tid >> 4;
    int m0 = blockIdx.y * 64, n0 = blockIdx.x * 64;
    float acc[4][4] = {};
    for (int k0 = 0; k0 < Kd; k0 += 32) {
        #pragma unroll
        for (int i = 0; i < 8; ++i) {
            int idx = tid + i * 256;
            int r = idx >> 5, c = idx & 31;
            As[c][r] = A[(size_t)(m0 + r) * Kd + k0 + c];
            int rn = n0 + r;
            Bs[c][r] = (rn < N) ? Bw[(size_t)rn * Kd + k0 + c] : 0.f;
        }
        __syncthreads();
        #pragma unroll
        for (int kk = 0; kk < 32; ++kk) {
            float4 av = *(const float4*)&As[kk][ty * 4];
            float4 bv = *(const float4*)&Bs[kk][tx * 4];
            const float* avp = (const float*)&av;
            const float* bvp = (const float*)&bv;
            #pragma unroll
            for (int i = 0; i < 4; ++i)
                #pragma unroll
                for (int j = 0; j < 4; ++j)
                    acc[i][j] += avp[i] * bvp[j];
        }
        __syncthreads();
    }
    #pragma unroll
    for (int i = 0; i < 4; ++i) {
        int m = m0 + ty * 4 + i;
        #pragma unroll
        for (int j = 0; j < 4; ++j) {
            int n = n0 + tx * 4 + j;
            if (n >= N) continue;
            float v = acc[i][j];
            if (MODE == 0) {
                if (n < DI) C0[(size_t)m * DI + n] = v;
                else        C1[(size_t)m * DI + (n - DI)] = silu_f(v);
            } else if (MODE == 1) {
                C0[(size_t)m * N + n] = v;
            } else {
                if (n < 152) {
                    int kd = n / 38, c = n - kd * 38;
                    C0[(size_t)m * XPS + kd * KOFF + c] = v;
                }
            }
        }
    }
}

// ---------------- Depthwise 3x3 conv + bias + SiLU, 8-pixel row tile ----------------
__global__ __launch_bounds__(192)
void conv_kernel(const float* __restrict__ xc, const float* __restrict__ cw,
                 const float* __restrict__ cb, float* __restrict__ out) {
    int p0 = blockIdx.x * 8;     // 8 pixels, same row (8 | 64)
    int b = blockIdx.y;
    int c = threadIdx.x;
    int h = p0 >> 6, w0 = p0 & 63;
    float kw[9];
    #pragma unroll
    for (int j = 0; j < 9; ++j) kw[j] = cw[c * 9 + j];
    float xv[3][10];
    #pragma unroll
    for (int dh = 0; dh < 3; ++dh) {
        int hh = h + dh - 1;
        bool hv = (hh >= 0 && hh < HH);
        #pragma unroll
        for (int j = 0; j < 10; ++j) {
            int ww = w0 + j - 1;
            bool v = hv && (ww >= 0 && ww < WW);
            xv[dh][j] = v ? xc[((size_t)(b << 12) + (hh << 6) + ww) * DI + c] : 0.f;
        }
    }
    float bias = cb[c];
    #pragma unroll
    for (int w = 0; w < 8; ++w) {
        float acc = bias;
        #pragma unroll
        for (int dh = 0; dh < 3; ++dh)
            #pragma unroll
            for (int dc = 0; dc < 3; ++dc)
                acc += xv[dh][w + dc] * kw[dh * 3 + dc];
        out[((size_t)(b << 12) + p0 + w) * DI + c] = silu_f(acc);
    }
}

// ---------------- prep: fastA flag (flag=0 -> A[n] == -(n+1) everywhere) ----------------
__global__ __launch_bounds__(256)
void prep_kernel(const float* __restrict__ A_logs, int* __restrict__ flag) {
    int t = blockIdx.x * 256 + threadIdx.x;
    if (t >= KK * DI * NS) return;
    int n = t & 15;
    float an = -__expf(A_logs[t]);
    if (!(fabsf(an + (float)(n + 1)) < 1e-4f * (float)(n + 1))) atomicOr(flag, 1);
}

// ---------------- Paired scan phases ----------------
// Block = 192 threads (one d each). pair = blockIdx.y: (k0,k1) = (pair, pair+2).
// Block owns k0's chunk c walked FORWARD and k1's chunk NCHT-1-c walked BACKWARD
// over the SAME pixel window [p0 + r*s], r=0..CHL-1 (s = 1 or 64).
// xdbl rows are wave-uniform -> direct global reads (no LDS staging). Rolled loop
// (full unroll blew VGPR to 80 in R12 -> 70us; rolled = 48 VGPR, 50us measured).
// Phase 3 accumulates y in a per-thread-column LDS tile (no races, no barrier,
// no atomics, no memset), then CHL coalesced stores. pair0 -> yA, pair1 -> yB.
// carryB layout: [chunk][row][n]; sumD: [chunk][row]; row = (b*K+k)*DI+d.
template<int PHASE, int NCHT>
__global__ __launch_bounds__(192)
void scan_paired(const float* __restrict__ xconv, const float* __restrict__ xdblP,
                 const float* __restrict__ dtw, const float* __restrict__ dtb,
                 const float* __restrict__ A_logs, const float* __restrict__ Ds,
                 float* __restrict__ sumD, float* __restrict__ carryB,
                 float* __restrict__ yA, float* __restrict__ yB,
                 const int* __restrict__ flag) {
    constexpr int CHL = LL / NCHT;
    constexpr int NV4 = (PHASE == 3) ? (KOFF / 4) : 6;
    int c = blockIdx.x;
    int pair = blockIdx.y;
    int b = blockIdx.z;
    int d = threadIdx.x;
    int k0 = pair, k1 = pair + 2;
    int c2 = NCHT - 1 - c;
    int s = (pair == 0) ? 1 : 64;
    int p0 = pix_of(k0, c * CHL);
    __shared__ float sy[(PHASE == 3) ? (CHL * DI) : 4];

    if (PHASE == 3) {
        for (int idx = d; idx < CHL * DI; idx += DI) sy[idx] = 0.f;  // own column only
    }

    float wr0[RR], wr1[RR];
    #pragma unroll
    for (int r = 0; r < RR; ++r) {
        wr0[r] = dtw[(k0 * DI + d) * RR + r];
        wr1[r] = dtw[(k1 * DI + d) * RR + r];
    }
    float bias0 = dtb[k0 * DI + d], bias1 = dtb[k1 * DI + d];
    const float* alog0 = A_logs + (size_t)(k0 * DI + d) * NS;
    const float* alog1 = A_logs + (size_t)(k1 * DI + d) * NS;
    bool fastA = (*flag == 0);
    int row0 = (b * KK + k0) * DI + d;
    int row1 = (b * KK + k1) * DI + d;
    float h0[NS], h1[NS];
    if (PHASE == 1) {
        #pragma unroll
        for (int n = 0; n < NS; ++n) { h0[n] = 0.f; h1[n] = 0.f; }
    } else {
        const float4* ca = (const float4*)(carryB + ((size_t)c * NROW + row0) * NS);
        const float4* cb = (const float4*)(carryB + ((size_t)c2 * NROW + row1) * NS);
        #pragma unroll
        for (int q = 0; q < NS / 4; ++q) {
            float4 va = ca[q], vb = cb[q];
            h0[q * 4 + 0] = va.x; h0[q * 4 + 1] = va.y; h0[q * 4 + 2] = va.z; h0[q * 4 + 3] = va.w;
            h1[q * 4 + 0] = vb.x; h1[q * 4 + 1] = vb.y; h1[q * 4 + 2] = vb.z; h1[q * 4 + 3] = vb.w;
        }
    }
    float Dk0 = (PHASE == 3) ? Ds[k0 * DI + d] : 0.f;
    float Dk1 = (PHASE == 3) ? Ds[k1 * DI + d] : 0.f;
    float sum0 = 0.f, sum1 = 0.f;
    const float* ub = xconv + ((size_t)(b << 12) + p0) * DI + d;
    const float* xrow = xdblP + ((size_t)(b << 12) + p0) * XPS;
    intptr_t xstp = (intptr_t)s * XPS;
    intptr_t ustp = (intptr_t)s * DI;

    auto dstep = [&](const float* __restrict__ xr, float u, const float* wr, float biasv,
                     const float* alog, float Dkv, float* h, float& sd) -> float {
        float xrv[NV4 * 4];
        #pragma unroll
        for (int j = 0; j < NV4; ++j) ((float4*)xrv)[j] = ((const float4*)xr)[j];
        float dtraw = biasv;
        #pragma unroll
        for (int r = 0; r < RR; ++r) dtraw += xrv[r] * wr[r];
        float delta = softplus_f(dtraw);
        if (PHASE == 1) sd += delta;
        float du = delta * u;
        float y = 0.f;
        if (fastA) {
            float g = __expf(-delta);
            float a = 1.f;
            #pragma unroll
            for (int n = 0; n < NS; ++n) {
                a *= g;                       // a = g^(n+1) = exp(-(n+1)*delta)
                h[n] = a * h[n] + du * xrv[6 + n];
                if (PHASE == 3) y += h[n] * xrv[22 + n];
            }
        } else {
            #pragma unroll
            for (int n = 0; n < NS; ++n) {
                float a = __expf(delta * (-__expf(alog[n])));
                h[n] = a * h[n] + du * xrv[6 + n];
                if (PHASE == 3) y += h[n] * xrv[22 + n];
            }
        }
        if (PHASE == 3) y += u * Dkv;
        return y;
    };

    for (int i = 0; i < CHL; ++i) {
        int ri = CHL - 1 - i;
        float u0 = ub[(intptr_t)i * ustp];
        float u1 = ub[(intptr_t)ri * ustp];
        float y0 = dstep(xrow + (intptr_t)i * xstp + k0 * KOFF, u0, wr0, bias0, alog0, Dk0, h0, sum0);
        float y1 = dstep(xrow + (intptr_t)ri * xstp + k1 * KOFF, u1, wr1, bias1, alog1, Dk1, h1, sum1);
        if (PHASE == 3) {
            sy[i * DI + d] += y0;        // own column: no races, no sync
            sy[ri * DI + d] += y1;
        }
    }

    if (PHASE == 3) {
        float* yo = ((pair == 0) ? yA : yB) + ((size_t)(b << 12) + p0) * DI + d;
        for (int r = 0; r < CHL; ++r) yo[(intptr_t)r * ustp] = sy[r * DI + d];
    } else {
        float4* ca = (float4*)(carryB + ((size_t)c * NROW + row0) * NS);
        float4* cb = (float4*)(carryB + ((size_t)c2 * NROW + row1) * NS);
        #pragma unroll
        for (int q = 0; q < NS / 4; ++q) {
            float4 va, vb;
            va.x = h0[q * 4 + 0]; va.y = h0[q * 4 + 1]; va.z = h0[q * 4 + 2]; va.w = h0[q * 4 + 3];
            vb.x = h1[q * 4 + 0]; vb.y = h1[q * 4 + 1]; vb.z = h1[q * 4 + 2]; vb.w = h1[q * 4 + 3];
            ca[q] = va; cb[q] = vb;
        }
        sumD[(size_t)c * NROW + row0] = sum0;
        sumD[(size_t)c2 * NROW + row1] = sum1;
    }
}

// ---------------- Phase 2: sequential scan over chunk carries ----------------
// a(chunk) reconstructed exactly: prod_i exp(An*d_i) == exp(An * sum d_i)
template<int NCHT>
__global__ __launch_bounds__(256)
void scan_chunks(const float* __restrict__ sumD, const float* __restrict__ A_logs,
                 float* __restrict__ carryB) {
    int t = blockIdx.x * 256 + threadIdx.x;
    if (t >= NROW * NS) return;
    int row = t >> 4, n = t & 15;
    int kd = row % (KK * DI);
    float An = -__expf(A_logs[(size_t)kd * NS + n]);
    float h = 0.f;
    #pragma unroll 4
    for (int c = 0; c < NCHT; ++c) {
        size_t idx = (size_t)c * (NROW * NS) + t;
        float bb = carryB[idx];
        carryB[idx] = h;       // exclusive prefix = h_in for chunk c
        float a = __expf(An * sumD[(size_t)c * NROW + row]);
        h = a * h + bb;
    }
}

// ---------------- LayerNorm * z  (y = yA + yB) ----------------
__global__ __launch_bounds__(256)
void ln_kernel(const float* __restrict__ yA, const float* __restrict__ yB,
               const float* __restrict__ z_silu,
               const float* __restrict__ nw, const float* __restrict__ nb,
               float* __restrict__ out) {
    int pg = blockIdx.x * 4 + (threadIdx.x >> 6);
    int lane = threadIdx.x & 63;
    const float* ya = yA + (size_t)pg * DI;
    const float* yb = yB + (size_t)pg * DI;
    float v0 = ya[lane] + yb[lane];
    float v1 = ya[lane + 64] + yb[lane + 64];
    float v2 = ya[lane + 128] + yb[lane + 128];
    float s = v0 + v1 + v2;
    float sq = v0 * v0 + v1 * v1 + v2 * v2;
    #pragma unroll
    for (int m = 32; m >= 1; m >>= 1) {
        s  += __shfl_xor(s, m, 64);
        sq += __shfl_xor(sq, m, 64);
    }
    float mu = s * (1.f / 192.f);
    float var = sq * (1.f / 192.f) - mu * mu;
    float rs = rsqrtf(var + 1e-5f);
    const float* zr = z_silu + (size_t)pg * DI;
    float* o = out + (size_t)pg * DI;
    float vv[3] = {v0, v1, v2};
    #pragma unroll
    for (int j = 0; j < 3; ++j) {
        int c = lane + j * 64;
        o[c] = (nw[c] * (vv[j] - mu) * rs + nb[c]) * zr[c];
    }
}

extern "C" void kernel_launch(void* const* d_in, const int* in_sizes, int n_in,
                              void* d_out, int out_size, void* d_ws, size_t ws_size,
                              hipStream_t stream) {
    const float* x        = (const float*)d_in[0];
    const float* in_projw = (const float*)d_in[1];
    const float* conv_w   = (const float*)d_in[2];
    const float* conv_b   = (const float*)d_in[3];
    const float* x_projw  = (const float*)d_in[4];
    const float* dt_w     = (const float*)d_in[5];
    const float* dt_b     = (const float*)d_in[6];
    const float* A_logs   = (const float*)d_in[7];
    const float* Ds       = (const float*)d_in[8];
    const float* nw       = (const float*)d_in[9];
    const float* nb       = (const float*)d_in[10];
    const float* opw      = (const float*)d_in[11];
    float* out = (float*)d_out;
    float* ws = (float*)d_ws;

    const size_t SZ = (size_t)B_ * LL * DI;          // 3,145,728
    const size_t XD = (size_t)B_ * LL * XPS;         // 2,621,440
    const size_t CAR256 = (size_t)NROW * 256 * NS;   // 12,582,912
    const size_t CAR128 = (size_t)NROW * 128 * NS;   //  6,291,456
    const size_t need256 = (4 * SZ + XD + CAR256 + (size_t)NROW * 256 + 16) * sizeof(float);
    bool big = (ws_size >= need256);
    const size_t CAR = big ? CAR256 : CAR128;
    const int NCH = big ? 256 : 128;

    float* z_silu = ws;
    float* yA     = ws + SZ;            // in_proj staging (xc_raw), reused as yA
    float* xconv  = ws + 2 * SZ;        // reused as yln after phase 3
    float* yB     = ws + 3 * SZ;
    float* xdblP  = ws + 4 * SZ;
    float* carryB = ws + 4 * SZ + XD;
    float* sumD   = carryB + CAR;
    int*   flag   = (int*)(sumD + (size_t)NROW * NCH);
    float* xc_raw = yA;
    float* yln    = xconv;

    gemm_kernel<0><<<dim3(6, 256), 256, 0, stream>>>(x, in_projw, xc_raw, z_silu,
                                                     B_ * LL, 2 * DI, DM);
    hipMemsetAsync(flag, 0, sizeof(int), stream);
    prep_kernel<<<(KK * DI * NS + 255) / 256, 256, 0, stream>>>(A_logs, flag);
    conv_kernel<<<dim3(LL / 8, B_), DI, 0, stream>>>(xc_raw, conv_w, conv_b, xconv);
    // x_dbl for all 4 directions in one pixel-order GEMM (152 = 4*38 outputs)
    gemm_kernel<2><<<dim3(3, 256), 256, 0, stream>>>(xconv, x_projw, xdblP, nullptr,
                                                     B_ * LL, 152, DI);

    if (big) {
        scan_paired<1, 256><<<dim3(256, 2, B_), 192, 0, stream>>>(xconv, xdblP, dt_w, dt_b,
                                                                  A_logs, Ds, sumD, carryB, nullptr, nullptr, flag);
        scan_chunks<256><<<(NROW * NS + 255) / 256, 256, 0, stream>>>(sumD, A_logs, carryB);
        scan_paired<3, 256><<<dim3(256, 2, B_), 192, 0, stream>>>(xconv, xdblP, dt_w, dt_b,
                                                                  A_logs, Ds, sumD, carryB, yA, yB, flag);
    } else {
        scan_paired<1, 128><<<dim3(128, 2, B_), 192, 0, stream>>>(xconv, xdblP, dt_w, dt_b,
                                                                  A_logs, Ds, sumD, carryB, nullptr, nullptr, flag);
        scan_chunks<128><<<(NROW * NS + 255) / 256, 256, 0, stream>>>(sumD, A_logs, carryB);
        scan_paired<3, 128><<<dim3(128, 2, B_), 192, 0, stream>>>(xconv, xdblP, dt_w, dt_b,
                                                                  A_logs, Ds, sumD, carryB, yA, yB, flag);
    }
    ln_kernel<<<(B_ * LL) / 4, 256, 0, stream>>>(yA, yB, z_silu, nw, nb, yln);
    gemm_kernel<1><<<dim3(2, 256), 256, 0, stream>>>(yln, opw, out, nullptr,
                                                     B_ * LL, DM, DI);
}